// Round 1
// baseline (45638.800 us; speedup 1.0000x reference)
//
#include <hip/hip_runtime.h>
#include <math.h>

// ---------------- constants ----------------
#define T_STEPS 8192
#define IN_DIM  1024
#define HD      1024
#define ZD      4096          // 4 gates * HD, order [i, j, f, o]
#define G2      64            // phase-2 workgroups (each owns 16 h-cols x 4 gates)
#define B2      512           // phase-2 block size (8 waves)

typedef short  short8 __attribute__((ext_vector_type(8)));
typedef float  f32x4  __attribute__((ext_vector_type(4)));

__device__ __forceinline__ unsigned short f2bf(float f) {
    unsigned u = __float_as_uint(f);
    unsigned r = (u + 0x7fffu + ((u >> 16) & 1u)) >> 16;
    return (unsigned short)r;
}

// ---------------- phase 0: pack Wx (rows 0..1023 of W) into bf16 tile layout ----
// Wt[tile_n][tile_k][col 0..127][kk 0..31], elem = Wx[tile_k*32+kk][tile_n*128+col]
__global__ void wt_pack(const float* __restrict__ W, unsigned short* __restrict__ Wt) {
    int idx = blockIdx.x * 256 + threadIdx.x;      // 0 .. 4M-1
    int k = idx >> 12;                             // 0..1023
    int c = idx & 4095;                            // 0..4095
    float v = W[(size_t)k * ZD + c];               // coalesced read
    int tn = c >> 7, col = c & 127;
    int tk = k >> 5, kk = k & 31;
    Wt[(((size_t)(tn * 32 + tk) * 128 + col) << 5) + kk] = f2bf(v);
}

// ---------------- phase 1: ZX = x @ Wx + b (bf16 MFMA, fp32 accum) --------------
#define BM 128
#define BN 128
#define BKK 32
#define LDA 40    // padded LDS stride (bf16 elems): 80B = 20 banks, 16B-aligned rows

__global__ __launch_bounds__(256) void zx_gemm(const float* __restrict__ x,
                                               const unsigned short* __restrict__ Wt,
                                               const float* __restrict__ b,
                                               float* __restrict__ zx) {
    __shared__ unsigned short As[128 * LDA];
    __shared__ unsigned short Bs[128 * LDA];
    const int tid  = threadIdx.x;
    const int wave = tid >> 6, lane = tid & 63;
    const int wr = wave & 1, wc = wave >> 1;
    const int m0 = blockIdx.y * BM, n0 = blockIdx.x * BN;
    const int quad = lane >> 4, l16 = lane & 15;

    f32x4 acc[4][4] = {};
    float bias[4];
#pragma unroll
    for (int j = 0; j < 4; ++j) bias[j] = b[n0 + wc * 64 + j * 16 + l16];

    for (int it = 0; it < IN_DIM / BKK; ++it) {
        const int k0 = it * BKK;
        // stage A: x[m0..+127][k0..+31] fp32 -> bf16 LDS
        {
            int r  = tid >> 3;          // 0..31
            int k4 = (tid & 7) * 4;
#pragma unroll
            for (int p = 0; p < 4; ++p) {
                int rr = r + p * 32;
                float4 v = *(const float4*)&x[(size_t)(m0 + rr) * IN_DIM + k0 + k4];
                unsigned p0 = (unsigned)f2bf(v.x) | ((unsigned)f2bf(v.y) << 16);
                unsigned p1 = (unsigned)f2bf(v.z) | ((unsigned)f2bf(v.w) << 16);
                *(uint2*)&As[rr * LDA + k4] = make_uint2(p0, p1);
            }
        }
        // stage B: pre-packed contiguous 8KB tile -> LDS (pad stride 40)
        {
            const uint4* src = (const uint4*)(Wt + ((size_t)(n0 >> 7) * 32 + it) * 4096);
#pragma unroll
            for (int p = 0; p < 2; ++p) {
                int id = tid * 2 + p;           // 0..511
                int col = id >> 2, kp = id & 3;
                uint4 v = src[id];
                *(uint4*)&Bs[col * LDA + kp * 8] = v;
            }
        }
        __syncthreads();
        short8 af[4], bfr[4];
#pragma unroll
        for (int i = 0; i < 4; ++i)
            af[i] = *(const short8*)&As[(wr * 64 + i * 16 + l16) * LDA + quad * 8];
#pragma unroll
        for (int j = 0; j < 4; ++j)
            bfr[j] = *(const short8*)&Bs[(wc * 64 + j * 16 + l16) * LDA + quad * 8];
#pragma unroll
        for (int i = 0; i < 4; ++i)
#pragma unroll
            for (int j = 0; j < 4; ++j)
                acc[i][j] = __builtin_amdgcn_mfma_f32_16x16x32_bf16(af[i], bfr[j], acc[i][j], 0, 0, 0);
        __syncthreads();
    }
    // epilogue: D row = quad*4 + reg, col = l16
#pragma unroll
    for (int i = 0; i < 4; ++i) {
        int row = m0 + wr * 64 + i * 16 + quad * 4;
#pragma unroll
        for (int j = 0; j < 4; ++j) {
            int col = n0 + wc * 64 + j * 16 + l16;
#pragma unroll
            for (int r = 0; r < 4; ++r)
                zx[(size_t)(row + r) * ZD + col] = acc[i][j][r] + bias[j];
        }
    }
}

// ---------------- phase 2: sequential recurrence (cooperative, 64 WGs) ----------
// WG g owns h-cols [16g,16g+16) and z-cols {16g+cidx + 1024*gate}.
// Thread t: seg = t>>6 (h-elems [128seg,128seg+128)), lane = t&63 -> (gate,cidx).
// Wh slice held in 128 VGPRs/thread. One grid barrier per step (flag array).
__global__ __launch_bounds__(B2, 2) void lstm_seq(const float* __restrict__ W,
                                                  const float* __restrict__ zx,
                                                  float* __restrict__ out,
                                                  float* hbuf, int* flags) {
    __shared__ float lds_h[HD];
    __shared__ float pbuf[B2];
    __shared__ float zlds[64];
    const int g    = blockIdx.x;
    const int t    = threadIdx.x;
    const int seg  = t >> 6;           // 0..7
    const int lane = t & 63;
    const int gate = lane >> 4;        // 0..3  [i,j,f,o]
    const int cidx = lane & 15;
    const int zcol = g * 16 + cidx + (gate << 10);

    // load Wh slice into registers: Wh rows are W rows 1024..2047
    float w[128];
#pragma unroll
    for (int j = 0; j < 128; ++j)
        w[j] = W[(size_t)(IN_DIM + (seg << 7) + j) * ZD + zcol];

    float c_state = 0.f;

    for (int s = 0; s < T_STEPS; ++s) {
        // ---- grid barrier: wait until every WG has published h_s ----
        if (s > 0 && t < 64) {
            while (true) {
                int f = __hip_atomic_load(&flags[lane], __ATOMIC_RELAXED,
                                          __HIP_MEMORY_SCOPE_AGENT);
                if (__all(f >= s)) break;
                __builtin_amdgcn_s_sleep(2);
            }
        }
        __syncthreads();
        // ---- stage h_s into LDS (device-coherent loads) ----
        const float* hsrc = hbuf + ((s & 1) << 10);
        if (t < 256) {
#pragma unroll
            for (int i = 0; i < 4; ++i)
                lds_h[(i << 8) + t] = __hip_atomic_load(&hsrc[(i << 8) + t],
                                                        __ATOMIC_RELAXED,
                                                        __HIP_MEMORY_SCOPE_AGENT);
        }
        float zxv = 0.f;
        if (t < 64)   // prefetch x-part, consumed after reduction
            zxv = zx[(size_t)s * ZD + (size_t)(t >> 4) * 1024 + g * 16 + (t & 15)];
        __syncthreads();
        // ---- 128 FMAs against register weights, h broadcast from LDS ----
        float a0 = 0.f, a1 = 0.f, a2 = 0.f, a3 = 0.f;
        const float4* hp = (const float4*)&lds_h[seg << 7];
#pragma unroll
        for (int j4 = 0; j4 < 32; ++j4) {
            float4 hv = hp[j4];
            a0 = fmaf(w[j4 * 4 + 0], hv.x, a0);
            a1 = fmaf(w[j4 * 4 + 1], hv.y, a1);
            a2 = fmaf(w[j4 * 4 + 2], hv.z, a2);
            a3 = fmaf(w[j4 * 4 + 3], hv.w, a3);
        }
        pbuf[t] = (a0 + a1) + (a2 + a3);
        __syncthreads();
        // ---- reduce 8 segments per z-col, add x-part ----
        if (t < 64) {
            float z = zxv;
#pragma unroll
            for (int ss = 0; ss < 8; ++ss) z += pbuf[(ss << 6) + t];
            zlds[t] = z;
        }
        __syncthreads();
        // ---- gates + state update (wave-0 lanes 0..15, lockstep with t==0) ----
        if (t < 16) {
            float zi = zlds[t], zj = zlds[16 + t], zf = zlds[32 + t], zo = zlds[48 + t];
            float fg = 1.f / (1.f + expf(-(zf + 1.0f)));   // FORGET_BIAS = 1.0
            float ig = 1.f / (1.f + expf(-zi));
            float og = 1.f / (1.f + expf(-zo));
            c_state = c_state * fg + ig * tanhf(zj);
            float h = tanhf(c_state) * og;
            out[(size_t)s * HD + g * 16 + t] = h;
            __hip_atomic_store(&hbuf[(((s + 1) & 1) << 10) + g * 16 + t], h,
                               __ATOMIC_RELAXED, __HIP_MEMORY_SCOPE_AGENT);
        }
        if (t == 0) {
            __threadfence();   // drain h stores (vmcnt) before publishing
            __hip_atomic_store(&flags[g], s + 1, __ATOMIC_RELAXED,
                               __HIP_MEMORY_SCOPE_AGENT);
        }
    }
}

// ---------------- launch ----------------
extern "C" void kernel_launch(void* const* d_in, const int* in_sizes, int n_in,
                              void* d_out, int out_size, void* d_ws, size_t ws_size,
                              hipStream_t stream) {
    const float* x = (const float*)d_in[0];   // [8192,1024]
    const float* W = (const float*)d_in[1];   // [2048,4096]
    const float* b = (const float*)d_in[2];   // [4096]
    float* out = (float*)d_out;               // [8192,1024]

    char* ws = (char*)d_ws;
    // ws layout: zx 128MB | hbuf 8KB | flags 4KB | Wt 8MB   (~136.1 MB total)
    float*          zxp   = (float*)ws;
    const size_t    ZXB   = (size_t)T_STEPS * ZD * sizeof(float);   // 134217728
    float*          hbuf  = (float*)(ws + ZXB);
    int*            flags = (int*)(ws + ZXB + 8192);
    unsigned short* Wt    = (unsigned short*)(ws + ZXB + 12288);

    // zero h0 double-buffer + barrier flags (ws is poisoned 0xAA before each call)
    hipMemsetAsync(hbuf, 0, 12288, stream);

    // phase 0: pack Wx -> bf16 tiles
    wt_pack<<<dim3((IN_DIM * ZD) / 256), dim3(256), 0, stream>>>(W, Wt);

    // phase 1: ZX = x @ Wx + b
    zx_gemm<<<dim3(ZD / BN, T_STEPS / BM), dim3(256), 0, stream>>>(x, Wt, b, zxp);

    // phase 2: sequential recurrence (cooperative for guaranteed co-residency)
    void* args[] = { (void*)&W, (void*)&zxp, (void*)&out, (void*)&hbuf, (void*)&flags };
    hipLaunchCooperativeKernel((void*)lstm_seq, dim3(G2), dim3(B2), args, 0, stream);
}

// Round 2
// 17102.243 us; speedup vs baseline: 2.6686x; 2.6686x over previous
//
#include <hip/hip_runtime.h>
#include <math.h>

// ---------------- constants ----------------
#define T_STEPS 8192
#define IN_DIM  1024
#define HD      1024
#define ZD      4096          // 4 gates * HD, order [i, j, f, o]
#define G2      64            // phase-2 workgroups (each owns 16 h-cols x 4 gates)
#define B2      512           // phase-2 block size (8 waves)

typedef short  short8 __attribute__((ext_vector_type(8)));
typedef float  f32x4  __attribute__((ext_vector_type(4)));

__device__ __forceinline__ unsigned short f2bf(float f) {
    unsigned u = __float_as_uint(f);
    unsigned r = (u + 0x7fffu + ((u >> 16) & 1u)) >> 16;
    return (unsigned short)r;
}

// ---------------- phase 0: pack Wx (rows 0..1023 of W) into bf16 tile layout ----
// Wt[tile_n][tile_k][col 0..127][kk 0..31], elem = Wx[tile_k*32+kk][tile_n*128+col]
__global__ void wt_pack(const float* __restrict__ W, unsigned short* __restrict__ Wt) {
    int idx = blockIdx.x * 256 + threadIdx.x;      // 0 .. 4M-1
    int k = idx >> 12;                             // 0..1023
    int c = idx & 4095;                            // 0..4095
    float v = W[(size_t)k * ZD + c];               // coalesced read
    int tn = c >> 7, col = c & 127;
    int tk = k >> 5, kk = k & 31;
    Wt[(((size_t)(tn * 32 + tk) * 128 + col) << 5) + kk] = f2bf(v);
}

// ---------------- phase 1: ZX = x @ Wx + b (bf16 MFMA, fp32 accum) --------------
#define BM 128
#define BN 128
#define BKK 32
#define LDA 40    // padded LDS stride (bf16 elems): 80B = 20 banks, 16B-aligned rows

__global__ __launch_bounds__(256) void zx_gemm(const float* __restrict__ x,
                                               const unsigned short* __restrict__ Wt,
                                               const float* __restrict__ b,
                                               float* __restrict__ zx) {
    __shared__ unsigned short As[128 * LDA];
    __shared__ unsigned short Bs[128 * LDA];
    const int tid  = threadIdx.x;
    const int wave = tid >> 6, lane = tid & 63;
    const int wr = wave & 1, wc = wave >> 1;
    const int m0 = blockIdx.y * BM, n0 = blockIdx.x * BN;
    const int quad = lane >> 4, l16 = lane & 15;

    f32x4 acc[4][4] = {};
    float bias[4];
#pragma unroll
    for (int j = 0; j < 4; ++j) bias[j] = b[n0 + wc * 64 + j * 16 + l16];

    for (int it = 0; it < IN_DIM / BKK; ++it) {
        const int k0 = it * BKK;
        // stage A: x[m0..+127][k0..+31] fp32 -> bf16 LDS
        {
            int r  = tid >> 3;          // 0..31
            int k4 = (tid & 7) * 4;
#pragma unroll
            for (int p = 0; p < 4; ++p) {
                int rr = r + p * 32;
                float4 v = *(const float4*)&x[(size_t)(m0 + rr) * IN_DIM + k0 + k4];
                unsigned p0 = (unsigned)f2bf(v.x) | ((unsigned)f2bf(v.y) << 16);
                unsigned p1 = (unsigned)f2bf(v.z) | ((unsigned)f2bf(v.w) << 16);
                *(uint2*)&As[rr * LDA + k4] = make_uint2(p0, p1);
            }
        }
        // stage B: pre-packed contiguous 8KB tile -> LDS (pad stride 40)
        {
            const uint4* src = (const uint4*)(Wt + ((size_t)(n0 >> 7) * 32 + it) * 4096);
#pragma unroll
            for (int p = 0; p < 2; ++p) {
                int id = tid * 2 + p;           // 0..511
                int col = id >> 2, kp = id & 3;
                uint4 v = src[id];
                *(uint4*)&Bs[col * LDA + kp * 8] = v;
            }
        }
        __syncthreads();
        short8 af[4], bfr[4];
#pragma unroll
        for (int i = 0; i < 4; ++i)
            af[i] = *(const short8*)&As[(wr * 64 + i * 16 + l16) * LDA + quad * 8];
#pragma unroll
        for (int j = 0; j < 4; ++j)
            bfr[j] = *(const short8*)&Bs[(wc * 64 + j * 16 + l16) * LDA + quad * 8];
#pragma unroll
        for (int i = 0; i < 4; ++i)
#pragma unroll
            for (int j = 0; j < 4; ++j)
                acc[i][j] = __builtin_amdgcn_mfma_f32_16x16x32_bf16(af[i], bfr[j], acc[i][j], 0, 0, 0);
        __syncthreads();
    }
    // epilogue: D row = quad*4 + reg, col = l16
#pragma unroll
    for (int i = 0; i < 4; ++i) {
        int row = m0 + wr * 64 + i * 16 + quad * 4;
#pragma unroll
        for (int j = 0; j < 4; ++j) {
            int col = n0 + wc * 64 + j * 16 + l16;
#pragma unroll
            for (int r = 0; r < 4; ++r)
                zx[(size_t)(row + r) * ZD + col] = acc[i][j][r] + bias[j];
        }
    }
}

// ---------------- fast activations (critical path) ----------------
__device__ __forceinline__ float sigmoid_fast(float x) {
    float e = __expf(-x);
    return __builtin_amdgcn_rcpf(1.f + e);
}
__device__ __forceinline__ float tanh_fast(float x) {
    // 1 - 2/(e^{2x}+1); e=inf -> 1, e=0 -> -1 (no NaN at extremes)
    float e = __expf(2.f * x);
    return 1.f - 2.f * __builtin_amdgcn_rcpf(e + 1.f);
}

// ---------------- phase 2: sequential recurrence (cooperative, 64 WGs) ----------
// WG g owns h-cols [16g,16g+16) and z-cols {16g+cidx + 1024*gate}.
// Thread t: seg = t>>6 (h rows [128seg,128seg+128)), lane = t&63 -> (gate,cidx).
// Wh slice in 128 regs/thread. h exchange: tagged 8B packets {fp32,step} in a
// parity double-buffer; tag rides with data -> ONE LLC round trip, no fences.
__global__ __launch_bounds__(B2, 2) void lstm_seq(const float* __restrict__ W,
                                                  const float* __restrict__ zx,
                                                  float* __restrict__ out,
                                                  unsigned long long* htag) {
    __shared__ float lds_h[HD];
    __shared__ float pbuf[B2];
    __shared__ float zx_lds[2][64];
    const int g    = blockIdx.x;
    const int t    = threadIdx.x;
    const int seg  = t >> 6;           // 0..7
    const int lane = t & 63;
    const int gate = lane >> 4;        // 0..3  [i,j,f,o]
    const int cidx = lane & 15;
    const int zcol = g * 16 + cidx + (gate << 10);

    // load Wh slice into registers: Wh rows are W rows 1024..2047
    float w[128];
#pragma unroll
    for (int j = 0; j < 128; ++j)
        w[j] = W[(size_t)(IN_DIM + (seg << 7) + j) * ZD + zcol];

    // preload zx row 0 (wave 1); consumed in phase C of step 0 (after syncs)
    if (t >= 64 && t < 128) {
        int l = t - 64;
        zx_lds[0][l] = zx[(size_t)0 * ZD + (size_t)(l >> 4) * 1024 + g * 16 + (l & 15)];
    }

    float c_state = 0.f;

    for (int s = 0; s < T_STEPS; ++s) {
        // ---- A: acquire h_s (spin on embedded tag), stage into LDS ----
        {
            const unsigned long long* src = htag + ((s & 1) << 10);
#pragma unroll
            for (int i = 0; i < 2; ++i) {
                int idx = (i << 9) + t;          // t and t+512
                unsigned long long v;
                do {
                    v = __hip_atomic_load(&src[idx], __ATOMIC_RELAXED,
                                          __HIP_MEMORY_SCOPE_AGENT);
                } while ((unsigned)(v >> 32) != (unsigned)s);
                lds_h[idx] = __uint_as_float((unsigned)v);
            }
        }
        // wave 1: issue zx prefetch for step s+1 (HBM latency hidden behind FMA)
        float znext = 0.f;
        if (t >= 64 && t < 128 && s + 1 < T_STEPS) {
            int l = t - 64;
            znext = zx[(size_t)(s + 1) * ZD + (size_t)(l >> 4) * 1024 + g * 16 + (l & 15)];
        }
        __syncthreads();                         // lds_h ready
        // ---- B: 128 FMAs against register weights ----
        float a0 = 0.f, a1 = 0.f, a2 = 0.f, a3 = 0.f;
        const float4* hp = (const float4*)&lds_h[seg << 7];
#pragma unroll
        for (int j4 = 0; j4 < 32; ++j4) {
            float4 hv = hp[j4];
            a0 = fmaf(w[j4 * 4 + 0], hv.x, a0);
            a1 = fmaf(w[j4 * 4 + 1], hv.y, a1);
            a2 = fmaf(w[j4 * 4 + 2], hv.z, a2);
            a3 = fmaf(w[j4 * 4 + 3], hv.w, a3);
        }
        pbuf[t] = (a0 + a1) + (a2 + a3);
        if (t >= 64 && t < 128)                  // park prefetched zx for next step
            zx_lds[(s + 1) & 1][t - 64] = znext;
        __syncthreads();                         // pbuf ready
        // ---- C: wave 0 reduces, gates, publishes ----
        if (t < 64) {
            float z = zx_lds[s & 1][t];
#pragma unroll
            for (int ss = 0; ss < 8; ++ss) z += pbuf[(ss << 6) + t];
            // gate combine within the wave (no LDS, no sync)
            float zi = __shfl(z, cidx);
            float zj = __shfl(z, 16 + cidx);
            float zf = __shfl(z, 32 + cidx);
            float zo = __shfl(z, 48 + cidx);
            if (t < 16) {
                float fg = sigmoid_fast(zf + 1.0f);   // FORGET_BIAS = 1.0
                float ig = sigmoid_fast(zi);
                float og = sigmoid_fast(zo);
                c_state = c_state * fg + ig * tanh_fast(zj);
                float h = tanh_fast(c_state) * og;
                // publish {h, tag=s+1} as one 8B device-scope store (no fence)
                unsigned long long pv =
                    ((unsigned long long)(unsigned)(s + 1) << 32) |
                    (unsigned long long)__float_as_uint(h);
                __hip_atomic_store(&htag[(((s + 1) & 1) << 10) + g * 16 + t], pv,
                                   __ATOMIC_RELAXED, __HIP_MEMORY_SCOPE_AGENT);
                out[(size_t)s * HD + g * 16 + t] = h;  // off critical path
            }
        }
        __syncthreads();                         // protect lds_h/pbuf reuse
    }
}

// ---------------- launch ----------------
extern "C" void kernel_launch(void* const* d_in, const int* in_sizes, int n_in,
                              void* d_out, int out_size, void* d_ws, size_t ws_size,
                              hipStream_t stream) {
    const float* x = (const float*)d_in[0];   // [8192,1024]
    const float* W = (const float*)d_in[1];   // [2048,4096]
    const float* b = (const float*)d_in[2];   // [4096]
    float* out = (float*)d_out;               // [8192,1024]

    char* ws = (char*)d_ws;
    // ws layout: zx 128MB | htag 16KB | Wt 8MB
    float*              zxp  = (float*)ws;
    const size_t        ZXB  = (size_t)T_STEPS * ZD * sizeof(float);   // 134217728
    unsigned long long* htag = (unsigned long long*)(ws + ZXB);
    unsigned short*     Wt   = (unsigned short*)(ws + ZXB + 16384);

    // h_0 = 0 with tag 0 in both parity slots (ws is poisoned 0xAA each call)
    hipMemsetAsync(htag, 0, 16384, stream);

    // phase 0: pack Wx -> bf16 tiles
    wt_pack<<<dim3((IN_DIM * ZD) / 256), dim3(256), 0, stream>>>(W, Wt);

    // phase 1: ZX = x @ Wx + b
    zx_gemm<<<dim3(ZD / BN, T_STEPS / BM), dim3(256), 0, stream>>>(x, Wt, b, zxp);

    // phase 2: sequential recurrence (cooperative for guaranteed co-residency)
    void* args[] = { (void*)&W, (void*)&zxp, (void*)&out, (void*)&htag };
    hipLaunchCooperativeKernel((void*)lstm_seq, dim3(G2), dim3(B2), args, 0, stream);
}